// Round 3
// baseline (441.332 us; speedup 1.0000x reference)
//
#include <hip/hip_runtime.h>
#include <cstdint>
#include <cstddef>

// MaskEstimator: 24 independent 2-layer GLU MLPs (fp16 MFMA path).
// R3: barrier-free GEMMs. A/B MFMA fragments are loaded DIRECTLY from global
// (K-major rows are contiguous; one base pointer per frag + imm offsets for
// all 16 k-steps). No LDS, no __syncthreads in the K-loop -> compiler can
// pipeline loads with fine-grained vmcnt instead of the vmcnt(0)+barrier
// drain that capped R2 at 22% MfmaUtil. xh re-laid band-major. GLU epilogue
// splits tanh/sigm across lane parity (halves transcendentals). All prep
// casts fused into one kernel.

typedef _Float16 f16;
typedef _Float16 f16x8 __attribute__((ext_vector_type(8)));
typedef float floatx4 __attribute__((ext_vector_type(4)));

#define BT 2048   // B*T
#define NB 24

__device__ __forceinline__ int band_di(int b){ return 8 << (b >> 2); }
__device__ __forceinline__ int band_off2(int b){
  int g = b >> 2;
  return 2 * (32 * ((1 << g) - 1) + (b & 3) * (8 << g));
}

__device__ __forceinline__ float fsigm(float x){
  return __builtin_amdgcn_rcpf(1.f + __expf(-x));
}
__device__ __forceinline__ float ftanh(float x){
  return 1.f - 2.f * __builtin_amdgcn_rcpf(1.f + __expf(2.f * x));
}

// ---------------- prep: all casts/permutes in ONE kernel ----------------
// blocks [0,6144): x (2048,24,512) f32 -> xh2 (24,2048,512) f16 (band-major)
// blocks [6144,12288): W0 (24,512,1024) -> w0t (24,1024,512) f16, (a,g) interleave
// blocks [12288,12540): W1 (512,4032) -> w1t (4032,512) f16, band-local interleave
// blocks [12540,12652): biases permuted (fp32)
__global__ __launch_bounds__(256) void prep(const float* __restrict__ x,
                                            const float* __restrict__ W0,
                                            const float* __restrict__ W1,
                                            const float* __restrict__ b0,
                                            const float* __restrict__ b1,
                                            f16* __restrict__ xh2,
                                            f16* __restrict__ w0t,
                                            f16* __restrict__ w1t,
                                            float* __restrict__ b0p,
                                            float* __restrict__ b1p){
  __shared__ __align__(16) char smem[33792];
  int bid = blockIdx.x;
  int t = threadIdx.x;
  if (bid < 6144){
    // x transpose-cast: 2048 rows x 3 band-groups of 8
    int r = bid / 3, bg = bid - 3 * r;
    int band = bg * 8 + (t >> 5);
    int k16 = (t & 31) * 16;
    const float* src = x + ((size_t)(r * 24 + band)) * 512 + k16;
    float4 v0 = *(const float4*)(src + 0);
    float4 v1 = *(const float4*)(src + 4);
    float4 v2 = *(const float4*)(src + 8);
    float4 v3 = *(const float4*)(src + 12);
    f16x8 o0 = { (f16)v0.x,(f16)v0.y,(f16)v0.z,(f16)v0.w,
                 (f16)v1.x,(f16)v1.y,(f16)v1.z,(f16)v1.w };
    f16x8 o1 = { (f16)v2.x,(f16)v2.y,(f16)v2.z,(f16)v2.w,
                 (f16)v3.x,(f16)v3.y,(f16)v3.z,(f16)v3.w };
    f16* dst = xh2 + ((size_t)(band * 2048 + r)) * 512 + k16;
    *(f16x8*)(dst + 0) = o0;
    *(f16x8*)(dst + 8) = o1;
  } else if (bid < 12288){
    float (*tile)[33] = (float(*)[33])smem;
    int b2 = bid - 6144;
    int dt   = b2 & 7;
    int half = (b2 >> 3) & 1;
    int g    = (b2 >> 4) & 15;
    int band = b2 >> 8;
    int c0 = half * 512 + g * 32;
    int d0 = dt * 64;
    int r  = t >> 2;
    int cs = (t & 3) * 8;
    const float* src = W0 + ((size_t)(band * 512 + d0 + r)) * 1024 + c0 + cs;
    float4 v0 = *(const float4*)src;
    float4 v1 = *(const float4*)(src + 4);
    tile[r][cs+0]=v0.x; tile[r][cs+1]=v0.y; tile[r][cs+2]=v0.z; tile[r][cs+3]=v0.w;
    tile[r][cs+4]=v1.x; tile[r][cs+5]=v1.y; tile[r][cs+6]=v1.z; tile[r][cs+7]=v1.w;
    __syncthreads();
    int i   = t >> 3;
    int ds8 = (t & 7) * 8;
    int prow = g * 64 + 2 * i + half;
    f16x8 o;
    #pragma unroll
    for (int k = 0; k < 8; ++k) o[k] = (f16)tile[ds8 + k][i];
    *(f16x8*)(w0t + ((size_t)(band * 1024 + prow)) * 512 + d0 + ds8) = o;
  } else if (bid < 12540){
    f16 (*tw)[520] = (f16(*)[520])smem;
    int jt = bid - 12288;           // 0..251
    int j16 = jt * 16;
    int band = 23;
    for (int b = 0; b < 24; ++b){ if (j16 < band_off2(b + 1)) { band = b; break; } }
    int off2 = band_off2(band), di = band_di(band);
    int p0 = j16 - off2;
    int oca = off2 + (p0 >> 1);
    int ocg = oca + di;
    #pragma unroll
    for (int hh = 0; hh < 2; ++hh){
      int d = hh * 256 + t;
      const float* rowp = W1 + (size_t)d * 4032;
      float4 a0 = *(const float4*)(rowp + oca);
      float4 a1 = *(const float4*)(rowp + oca + 4);
      float4 g0 = *(const float4*)(rowp + ocg);
      float4 g1 = *(const float4*)(rowp + ocg + 4);
      float av[8] = {a0.x,a0.y,a0.z,a0.w,a1.x,a1.y,a1.z,a1.w};
      float gv[8] = {g0.x,g0.y,g0.z,g0.w,g1.x,g1.y,g1.z,g1.w};
      #pragma unroll
      for (int q = 0; q < 8; ++q){
        tw[2*q][d]   = (f16)av[q];
        tw[2*q+1][d] = (f16)gv[q];
      }
    }
    __syncthreads();
    int j = t & 15, dc = (t >> 4) * 32;
    f16x8 o[4];
    #pragma unroll
    for (int k = 0; k < 4; ++k) o[k] = *(const f16x8*)&tw[j][dc + k*8];
    f16* dst = w1t + (size_t)(j16 + j) * 512 + dc;
    #pragma unroll
    for (int k = 0; k < 4; ++k) *(f16x8*)(dst + k*8) = o[k];
  } else {
    int idx = (bid - 12540) * 256 + t;
    if (idx < NB * 1024){
      int p = idx & 1023;
      int base = idx & ~1023;
      b0p[idx] = b0[base + ((p & 1) ? 512 + (p >> 1) : (p >> 1))];
    } else {
      int j = idx - NB * 1024;
      if (j < 4032){
        int band = 23;
        for (int b = 0; b < 24; ++b){ if (j < band_off2(b + 1)) { band = b; break; } }
        int off2 = band_off2(band);
        int di = band_di(band);
        int p = j - off2;
        b1p[j] = b1[off2 + ((p & 1) ? di + (p >> 1) : (p >> 1))];
      }
    }
  }
}

// ---------------- GEMM1: barrier-free, direct-from-global frags ----------------
// 128x128 block tile, 4 waves 2x2 (wave 64x64). grid 3072, XCD swizzle.
__global__ __launch_bounds__(256) void gemm1(const f16* __restrict__ xh2,
                                             const f16* __restrict__ w0t,
                                             const float* __restrict__ b0p,
                                             f16* __restrict__ h){
  int bid = blockIdx.x;
  int wid = (bid & 7) * 384 + (bid >> 3);   // XCD-contiguous: 3 bands per XCD
  int band = wid >> 7;
  int mt = (wid >> 3) & 15;
  int nt = wid & 7;
  int t = threadIdx.x;
  int lane = t & 63, w = t >> 6;
  int wm = w & 1, wn = w >> 1;
  int quad = lane >> 4, lc = lane & 15;
  const int mrow0 = mt * 128;
  const int nrow0 = nt * 128;

  const f16* pA[4]; const f16* pB[4];
  #pragma unroll
  for (int i = 0; i < 4; ++i){
    pA[i] = xh2 + ((size_t)(band * 2048 + mrow0 + wm * 64 + i * 16 + lc)) * 512 + quad * 8;
    pB[i] = w0t + ((size_t)(band * 1024 + nrow0 + wn * 64 + i * 16 + lc)) * 512 + quad * 8;
  }
  floatx4 acc[4][4];
  #pragma unroll
  for (int i = 0; i < 4; ++i)
    #pragma unroll
    for (int j = 0; j < 4; ++j) acc[i][j] = floatx4{0.f, 0.f, 0.f, 0.f};

  #pragma unroll
  for (int s = 0; s < 16; ++s){           // K = 16 steps x 32
    f16x8 af[4], bf[4];
    #pragma unroll
    for (int i = 0; i < 4; ++i) af[i] = *(const f16x8*)(pA[i] + s * 32);
    #pragma unroll
    for (int i = 0; i < 4; ++i) bf[i] = *(const f16x8*)(pB[i] + s * 32);
    #pragma unroll
    for (int i = 0; i < 4; ++i)
      #pragma unroll
      for (int j = 0; j < 4; ++j)
        acc[i][j] = __builtin_amdgcn_mfma_f32_16x16x32_f16(af[i], bf[j], acc[i][j], 0, 0, 0);
  }

  // GLU epilogue: parity-split transcendentals (even lane: tanh, odd: sigm)
  #pragma unroll
  for (int j = 0; j < 4; ++j){
    int colp = nrow0 + wn * 64 + j * 16 + lc;
    float bias = b0p[band * 1024 + colp];
    #pragma unroll
    for (int i = 0; i < 4; ++i){
      int mbase = mrow0 + wm * 64 + i * 16 + quad * 4;
      #pragma unroll
      for (int r = 0; r < 4; ++r){
        float z = acc[i][j][r] + bias;
        float v = (lc & 1) ? fsigm(z) : ftanh(z);
        float vp = __shfl_xor(v, 1);
        if (!(lc & 1)){
          h[((size_t)band * BT + mbase + r) * 512 + (colp >> 1)] = (f16)(v * vp);
        }
      }
    }
  }
}

// ---------------- GEMM2: barrier-free, direct-from-global ----------------
// wave = 32 rows x (16*NF2) cols; 4 waves cover 128 rows.
template<int NF2>
__device__ __forceinline__ void gemm2_direct(const f16* __restrict__ hb,
                                             const f16* __restrict__ w1t,
                                             const float* __restrict__ b1p,
                                             float* __restrict__ out,
                                             int band, int mt, int joff){
  int t = threadIdx.x;
  int lane = t & 63, w = t >> 6;
  int quad = lane >> 4, lc = lane & 15;
  int off2 = band_off2(band);
  int jbase = off2 + joff;

  const f16* pA[2]; const f16* pB[NF2];
  #pragma unroll
  for (int i = 0; i < 2; ++i)
    pA[i] = hb + ((size_t)(mt * 128 + w * 32 + i * 16 + lc)) * 512 + quad * 8;
  #pragma unroll
  for (int j = 0; j < NF2; ++j)
    pB[j] = w1t + ((size_t)(jbase + j * 16 + lc)) * 512 + quad * 8;

  floatx4 acc[2][NF2];
  #pragma unroll
  for (int i = 0; i < 2; ++i)
    #pragma unroll
    for (int j = 0; j < NF2; ++j) acc[i][j] = floatx4{0.f, 0.f, 0.f, 0.f};

  #pragma unroll
  for (int s = 0; s < 16; ++s){
    f16x8 af[2], bf[NF2];
    #pragma unroll
    for (int i = 0; i < 2; ++i) af[i] = *(const f16x8*)(pA[i] + s * 32);
    #pragma unroll
    for (int j = 0; j < NF2; ++j) bf[j] = *(const f16x8*)(pB[j] + s * 32);
    #pragma unroll
    for (int i = 0; i < 2; ++i)
      #pragma unroll
      for (int j = 0; j < NF2; ++j)
        acc[i][j] = __builtin_amdgcn_mfma_f32_16x16x32_f16(af[i], bf[j], acc[i][j], 0, 0, 0);
  }
  int outbase = off2 >> 1;
  #pragma unroll
  for (int j = 0; j < NF2; ++j){
    int p = joff + j * 16 + lc;
    float bias = b1p[off2 + p];
    #pragma unroll
    for (int i = 0; i < 2; ++i){
      int mbase = mt * 128 + w * 32 + i * 16 + quad * 4;
      #pragma unroll
      for (int r = 0; r < 4; ++r){
        float z = acc[i][j][r] + bias;
        float v = (lc & 1) ? fsigm(z) : ftanh(z);
        float vp = __shfl_xor(v, 1);
        if (!(lc & 1)){
          out[(size_t)(mbase + r) * 2016 + outbase + (p >> 1)] = v * vp;
        }
      }
    }
  }
}

// grid 640: bands 0-15: 16 blocks (whole 2di<=128 cols); 16-19: 2x128-col
// tiles; 20-23: 4x128-col tiles.
__global__ __launch_bounds__(256) void gemm2(const f16* __restrict__ h,
                                             const f16* __restrict__ w1t,
                                             const float* __restrict__ b1p,
                                             float* __restrict__ out){
  int bid = blockIdx.x;
  int band, mt, joff, cls;
  if (bid < 256){
    band = bid >> 4; mt = bid & 15; joff = 0; cls = band >> 2;   // NF2 = 1<<cls
  } else if (bid < 384){
    int rel = bid - 256; band = 16 + (rel >> 5);
    int r2 = rel & 31; mt = r2 & 15; joff = (r2 >> 4) * 128; cls = 3;
  } else {
    int rel = bid - 384; band = 20 + (rel >> 6);
    int r2 = rel & 63; mt = r2 & 15; joff = (r2 >> 4) * 128; cls = 3;
  }
  const f16* hb = h + ((size_t)band << 20);
  switch (cls){
    case 0:  gemm2_direct<1>(hb, w1t, b1p, out, band, mt, joff); break;
    case 1:  gemm2_direct<2>(hb, w1t, b1p, out, band, mt, joff); break;
    case 2:  gemm2_direct<4>(hb, w1t, b1p, out, band, mt, joff); break;
    default: gemm2_direct<8>(hb, w1t, b1p, out, band, mt, joff); break;
  }
}

// ---------------- launch ----------------
extern "C" void kernel_launch(void* const* d_in, const int* in_sizes, int n_in,
                              void* d_out, int out_size, void* d_ws, size_t ws_size,
                              hipStream_t stream){
  const float* x  = (const float*)d_in[0];
  const float* W0 = (const float*)d_in[1];
  const float* b0 = (const float*)d_in[2];
  const float* W1 = (const float*)d_in[3];
  const float* b1 = (const float*)d_in[4];
  char* ws = (char*)d_ws;
  f16*   xh2  = (f16*)(ws);                       // 50,331,648 B (band-major)
  f16*   hbuf = (f16*)(ws + 50331648);            // 50,331,648 B
  f16*   w0t  = (f16*)(ws + 100663296);           // 25,165,824 B
  f16*   w1t  = (f16*)(ws + 125829120);           //  4,128,768 B
  float* b0p  = (float*)(ws + 129957888);         //     98,304 B
  float* b1p  = (float*)(ws + 130056192);         //     16,128 B

  prep <<<12652, 256, 0, stream>>>(x, W0, W1, b0, b1, xh2, w0t, w1t, b0p, b1p);
  gemm1<<<3072,  256, 0, stream>>>(xh2, w0t, b0p, hbuf);
  gemm2<<<640,   256, 0, stream>>>(hbuf, w1t, b1p, (float*)d_out);
}

// Round 4
// 333.301 us; speedup vs baseline: 1.3241x; 1.3241x over previous
//
#include <hip/hip_runtime.h>
#include <cstdint>
#include <cstddef>

// MaskEstimator: 24 independent 2-layer GLU MLPs (fp16 MFMA path).
// R4: revert to R2's LDS-staged GEMM structure (R3's direct-global frags were
// latency-bound: MfmaUtil 10.6%). Keep from R3: fused prep kernel, band-major
// xh2, parity-split GLU transcendentals. New: XCD swizzle on gemm2.

typedef _Float16 f16;
typedef _Float16 f16x8 __attribute__((ext_vector_type(8)));
typedef float floatx4 __attribute__((ext_vector_type(4)));

#define BT 2048   // B*T
#define NB 24

__device__ __forceinline__ int band_di(int b){ return 8 << (b >> 2); }
__device__ __forceinline__ int band_off2(int b){
  int g = b >> 2;
  return 2 * (32 * ((1 << g) - 1) + (b & 3) * (8 << g));
}

__device__ __forceinline__ float fsigm(float x){
  return __builtin_amdgcn_rcpf(1.f + __expf(-x));
}
__device__ __forceinline__ float ftanh(float x){
  return 1.f - 2.f * __builtin_amdgcn_rcpf(1.f + __expf(2.f * x));
}

__device__ __forceinline__ void gl_lds16(const void* g, void* l){
  __builtin_amdgcn_global_load_lds(
      (const __attribute__((address_space(1))) unsigned int*)g,
      (__attribute__((address_space(3))) unsigned int*)l, 16, 0, 0);
}

// ---------------- prep: all casts/permutes in ONE kernel ----------------
// blocks [0,6144): x (2048,24,512) f32 -> xh2 (24,2048,512) f16 (band-major)
// blocks [6144,12288): W0 (24,512,1024) -> w0t (24,1024,512) f16, (a,g) interleave
// blocks [12288,12540): W1 (512,4032) -> w1t (4032,512) f16, band-local interleave
// blocks [12540,12652): biases permuted (fp32)
__global__ __launch_bounds__(256) void prep(const float* __restrict__ x,
                                            const float* __restrict__ W0,
                                            const float* __restrict__ W1,
                                            const float* __restrict__ b0,
                                            const float* __restrict__ b1,
                                            f16* __restrict__ xh2,
                                            f16* __restrict__ w0t,
                                            f16* __restrict__ w1t,
                                            float* __restrict__ b0p,
                                            float* __restrict__ b1p){
  __shared__ __align__(16) char smem[33792];
  int bid = blockIdx.x;
  int t = threadIdx.x;
  if (bid < 6144){
    int r = bid / 3, bg = bid - 3 * r;
    int band = bg * 8 + (t >> 5);
    int k16 = (t & 31) * 16;
    const float* src = x + ((size_t)(r * 24 + band)) * 512 + k16;
    float4 v0 = *(const float4*)(src + 0);
    float4 v1 = *(const float4*)(src + 4);
    float4 v2 = *(const float4*)(src + 8);
    float4 v3 = *(const float4*)(src + 12);
    f16x8 o0 = { (f16)v0.x,(f16)v0.y,(f16)v0.z,(f16)v0.w,
                 (f16)v1.x,(f16)v1.y,(f16)v1.z,(f16)v1.w };
    f16x8 o1 = { (f16)v2.x,(f16)v2.y,(f16)v2.z,(f16)v2.w,
                 (f16)v3.x,(f16)v3.y,(f16)v3.z,(f16)v3.w };
    f16* dst = xh2 + ((size_t)(band * 2048 + r)) * 512 + k16;
    *(f16x8*)(dst + 0) = o0;
    *(f16x8*)(dst + 8) = o1;
  } else if (bid < 12288){
    float (*tile)[33] = (float(*)[33])smem;
    int b2 = bid - 6144;
    int dt   = b2 & 7;
    int half = (b2 >> 3) & 1;
    int g    = (b2 >> 4) & 15;
    int band = b2 >> 8;
    int c0 = half * 512 + g * 32;
    int d0 = dt * 64;
    int r  = t >> 2;
    int cs = (t & 3) * 8;
    const float* src = W0 + ((size_t)(band * 512 + d0 + r)) * 1024 + c0 + cs;
    float4 v0 = *(const float4*)src;
    float4 v1 = *(const float4*)(src + 4);
    tile[r][cs+0]=v0.x; tile[r][cs+1]=v0.y; tile[r][cs+2]=v0.z; tile[r][cs+3]=v0.w;
    tile[r][cs+4]=v1.x; tile[r][cs+5]=v1.y; tile[r][cs+6]=v1.z; tile[r][cs+7]=v1.w;
    __syncthreads();
    int i   = t >> 3;
    int ds8 = (t & 7) * 8;
    int prow = g * 64 + 2 * i + half;
    f16x8 o;
    #pragma unroll
    for (int k = 0; k < 8; ++k) o[k] = (f16)tile[ds8 + k][i];
    *(f16x8*)(w0t + ((size_t)(band * 1024 + prow)) * 512 + d0 + ds8) = o;
  } else if (bid < 12540){
    f16 (*tw)[520] = (f16(*)[520])smem;
    int jt = bid - 12288;           // 0..251
    int j16 = jt * 16;
    int band = 23;
    for (int b = 0; b < 24; ++b){ if (j16 < band_off2(b + 1)) { band = b; break; } }
    int off2 = band_off2(band), di = band_di(band);
    int p0 = j16 - off2;
    int oca = off2 + (p0 >> 1);
    int ocg = oca + di;
    #pragma unroll
    for (int hh = 0; hh < 2; ++hh){
      int d = hh * 256 + t;
      const float* rowp = W1 + (size_t)d * 4032;
      float4 a0 = *(const float4*)(rowp + oca);
      float4 a1 = *(const float4*)(rowp + oca + 4);
      float4 g0 = *(const float4*)(rowp + ocg);
      float4 g1 = *(const float4*)(rowp + ocg + 4);
      float av[8] = {a0.x,a0.y,a0.z,a0.w,a1.x,a1.y,a1.z,a1.w};
      float gv[8] = {g0.x,g0.y,g0.z,g0.w,g1.x,g1.y,g1.z,g1.w};
      #pragma unroll
      for (int q = 0; q < 8; ++q){
        tw[2*q][d]   = (f16)av[q];
        tw[2*q+1][d] = (f16)gv[q];
      }
    }
    __syncthreads();
    int j = t & 15, dc = (t >> 4) * 32;
    f16x8 o[4];
    #pragma unroll
    for (int k = 0; k < 4; ++k) o[k] = *(const f16x8*)&tw[j][dc + k*8];
    f16* dst = w1t + (size_t)(j16 + j) * 512 + dc;
    #pragma unroll
    for (int k = 0; k < 4; ++k) *(f16x8*)(dst + k*8) = o[k];
  } else {
    int idx = (bid - 12540) * 256 + t;
    if (idx < NB * 1024){
      int p = idx & 1023;
      int base = idx & ~1023;
      b0p[idx] = b0[base + ((p & 1) ? 512 + (p >> 1) : (p >> 1))];
    } else {
      int j = idx - NB * 1024;
      if (j < 4032){
        int band = 23;
        for (int b = 0; b < 24; ++b){ if (j < band_off2(b + 1)) { band = b; break; } }
        int off2 = band_off2(band);
        int di = band_di(band);
        int p = j - off2;
        b1p[j] = b1[off2 + ((p & 1) ? di + (p >> 1) : (p >> 1))];
      }
    }
  }
}

// ---------------- GEMM1: LDS-staged (R2 structure), parity GLU epilogue ------
// 128x128 tile, BK=64, 4 waves 2x2. grid 3072, XCD-contiguous swizzle.
__global__ __launch_bounds__(256) void gemm1(const f16* __restrict__ xh2,
                                             const f16* __restrict__ w0t,
                                             const float* __restrict__ b0p,
                                             f16* __restrict__ h){
  __shared__ __align__(16) f16 As[128 * 64];
  __shared__ __align__(16) f16 Bs[128 * 64];
  int bid = blockIdx.x;
  int wid = (bid & 7) * 384 + (bid >> 3);   // 3 bands per XCD slice
  int band = wid >> 7;
  int mt = (wid >> 3) & 15;
  int nt = wid & 7;
  int t = threadIdx.x;
  int lane = t & 63, w = t >> 6;
  int wm = w & 1, wn = w >> 1;
  int quad = lane >> 4, lc = lane & 15;
  const int mrow0 = mt * 128;
  const int nrow0 = nt * 128;

  const char* gA[4]; const char* gB[4];
  f16* lA[4]; f16* lB[4];
  #pragma unroll
  for (int p = 0; p < 4; ++p){
    int idx = p * 256 + t;
    int r = idx >> 3, s = idx & 7, l = s ^ (r & 7);
    gA[p] = (const char*)(xh2 + ((size_t)(band * 2048 + mrow0 + r)) * 512 + l * 8);
    gB[p] = (const char*)(w0t + ((size_t)(band * 1024 + nrow0 + r)) * 512 + l * 8);
    lA[p] = &As[idx * 8];
    lB[p] = &Bs[idx * 8];
  }
  int aoff[4], boff[4];
  #pragma unroll
  for (int i = 0; i < 4; ++i){
    int m = wm * 64 + i * 16 + lc;
    aoff[i] = (m * 64 + ((quad ^ (m & 7)) << 3)) * 2;
    int n = wn * 64 + i * 16 + lc;
    boff[i] = (n * 64 + ((quad ^ (n & 7)) << 3)) * 2;
  }
  const char* Ab = (const char*)As;
  const char* Bb = (const char*)Bs;

  floatx4 acc[4][4];
  #pragma unroll
  for (int i = 0; i < 4; ++i)
    #pragma unroll
    for (int j = 0; j < 4; ++j) acc[i][j] = floatx4{0.f, 0.f, 0.f, 0.f};

  for (int kb = 0; kb < 8; ++kb){
    #pragma unroll
    for (int p = 0; p < 4; ++p){ gl_lds16(gA[p], lA[p]); gA[p] += 128; }
    #pragma unroll
    for (int p = 0; p < 4; ++p){ gl_lds16(gB[p], lB[p]); gB[p] += 128; }
    __syncthreads();
    #pragma unroll
    for (int s2 = 0; s2 < 2; ++s2){
      f16x8 af[4], bf[4];
      #pragma unroll
      for (int i = 0; i < 4; ++i){
        af[i] = *(const f16x8*)(Ab + (aoff[i] ^ (s2 * 64)));
        bf[i] = *(const f16x8*)(Bb + (boff[i] ^ (s2 * 64)));
      }
      #pragma unroll
      for (int i = 0; i < 4; ++i)
        #pragma unroll
        for (int j = 0; j < 4; ++j)
          acc[i][j] = __builtin_amdgcn_mfma_f32_16x16x32_f16(af[i], bf[j], acc[i][j], 0, 0, 0);
    }
    __syncthreads();
  }
  // parity-split GLU: even lane computes tanh(a), odd computes sigm(g)
  #pragma unroll
  for (int j = 0; j < 4; ++j){
    int colp = nrow0 + wn * 64 + j * 16 + lc;
    float bias = b0p[band * 1024 + colp];
    #pragma unroll
    for (int i = 0; i < 4; ++i){
      int mbase = mrow0 + wm * 64 + i * 16 + quad * 4;
      #pragma unroll
      for (int r = 0; r < 4; ++r){
        float z = acc[i][j][r] + bias;
        float v = (lc & 1) ? fsigm(z) : ftanh(z);
        float vp = __shfl_xor(v, 1);
        if (!(lc & 1)){
          h[((size_t)band * BT + mbase + r) * 512 + (colp >> 1)] = (f16)(v * vp);
        }
      }
    }
  }
}

// ---------------- GEMM2: LDS-staged (R2 structure), parity GLU epilogue ------
template<int BN>
__device__ __forceinline__ void gemm2_tile(const f16* __restrict__ hb,
                                           const f16* __restrict__ w1t,
                                           const float* __restrict__ b1p,
                                           float* __restrict__ out,
                                           int band, int mt, int ntile,
                                           f16* As, f16* Bs){
  constexpr int WNW = (BN == 128) ? 2 : 1;
  constexpr int WMW = 4 / WNW;
  constexpr int MF = 128 / (WMW * 16);
  constexpr int NF = BN / (WNW * 16);
  int t = threadIdx.x;
  int lane = t & 63, w = t >> 6;
  int wm = (WNW == 2) ? (w & 1) : w;
  int wn = (WNW == 2) ? (w >> 1) : 0;
  int quad = lane >> 4, lc = lane & 15;
  int off2 = band_off2(band);
  int jbase = off2 + ntile * BN;

  constexpr int BCH = BN * 8;
  constexpr int BP = (BCH + 255) / 256;
  const char* gA[4]; const char* gB[BP];
  f16* lA[4]; f16* lB[BP];
  #pragma unroll
  for (int p = 0; p < 4; ++p){
    int idx = p * 256 + t;
    int r = idx >> 3, s = idx & 7, l = s ^ (r & 7);
    gA[p] = (const char*)(hb + ((size_t)(mt * 128 + r)) * 512 + l * 8);
    lA[p] = &As[idx * 8];
  }
  #pragma unroll
  for (int p = 0; p < BP; ++p){
    int idx = p * 256 + t;
    int r = idx >> 3, s = idx & 7, l = s ^ (r & 7);
    gB[p] = (const char*)(w1t + ((size_t)(jbase + r)) * 512 + l * 8);
    lB[p] = &Bs[idx * 8];
  }
  int aoff[MF], boff[NF];
  #pragma unroll
  for (int i = 0; i < MF; ++i){
    int m = wm * (MF * 16) + i * 16 + lc;
    aoff[i] = (m * 64 + ((quad ^ (m & 7)) << 3)) * 2;
  }
  #pragma unroll
  for (int j = 0; j < NF; ++j){
    int n = wn * (NF * 16) + j * 16 + lc;
    boff[j] = (n * 64 + ((quad ^ (n & 7)) << 3)) * 2;
  }
  const char* Ab = (const char*)As;
  const char* Bb = (const char*)Bs;

  floatx4 acc[MF][NF];
  #pragma unroll
  for (int i = 0; i < MF; ++i)
    #pragma unroll
    for (int j = 0; j < NF; ++j) acc[i][j] = floatx4{0.f, 0.f, 0.f, 0.f};

  for (int kb = 0; kb < 8; ++kb){
    #pragma unroll
    for (int p = 0; p < 4; ++p){ gl_lds16(gA[p], lA[p]); gA[p] += 128; }
    #pragma unroll
    for (int p = 0; p < BP; ++p){
      if ((BCH % 256 == 0) || (p * 256 + t) < BCH){
        gl_lds16(gB[p], lB[p]); gB[p] += 128;
      }
    }
    __syncthreads();
    #pragma unroll
    for (int s2 = 0; s2 < 2; ++s2){
      f16x8 af[MF], bf[NF];
      #pragma unroll
      for (int i = 0; i < MF; ++i)
        af[i] = *(const f16x8*)(Ab + (aoff[i] ^ (s2 * 64)));
      #pragma unroll
      for (int j = 0; j < NF; ++j)
        bf[j] = *(const f16x8*)(Bb + (boff[j] ^ (s2 * 64)));
      #pragma unroll
      for (int i = 0; i < MF; ++i)
        #pragma unroll
        for (int j = 0; j < NF; ++j)
          acc[i][j] = __builtin_amdgcn_mfma_f32_16x16x32_f16(af[i], bf[j], acc[i][j], 0, 0, 0);
    }
    __syncthreads();
  }
  int outbase = off2 >> 1;
  #pragma unroll
  for (int j = 0; j < NF; ++j){
    int p = ntile * BN + wn * (NF * 16) + j * 16 + lc;
    float bias = b1p[off2 + p];
    #pragma unroll
    for (int i = 0; i < MF; ++i){
      int mbase = mt * 128 + wm * (MF * 16) + i * 16 + quad * 4;
      #pragma unroll
      for (int r = 0; r < 4; ++r){
        float z = acc[i][j][r] + bias;
        float v = (lc & 1) ? fsigm(z) : ftanh(z);
        float vp = __shfl_xor(v, 1);
        if (!(lc & 1)){
          out[(size_t)(mbase + r) * 2016 + outbase + (p >> 1)] = v * vp;
        }
      }
    }
  }
}

// grid 640, XCD-swizzled. bands 0-15: 16 blocks; 16-19: 32; 20-23: 64.
__global__ __launch_bounds__(256) void gemm2(const f16* __restrict__ h,
                                             const f16* __restrict__ w1t,
                                             const float* __restrict__ b1p,
                                             float* __restrict__ out){
  __shared__ __align__(16) f16 As[128 * 64];
  __shared__ __align__(16) f16 Bs[128 * 64];
  int bid0 = blockIdx.x;
  int bid = (bid0 & 7) * 80 + (bid0 >> 3);   // XCD-contiguous slices of 80
  int band, mt, ntile, cls;
  if (bid < 256){
    band = bid >> 4; mt = bid & 15; ntile = 0; cls = band >> 2;
  } else if (bid < 384){
    int rel = bid - 256; band = 16 + (rel >> 5);
    int r2 = rel & 31; mt = r2 & 15; ntile = r2 >> 4; cls = 4;
  } else {
    int rel = bid - 384; band = 20 + (rel >> 6);
    int r2 = rel & 63; mt = r2 & 15; ntile = r2 >> 4; cls = 5;
  }
  const f16* hb = h + ((size_t)band << 20);
  switch (cls){
    case 0:  gemm2_tile<16 >(hb, w1t, b1p, out, band, mt, ntile, As, Bs); break;
    case 1:  gemm2_tile<32 >(hb, w1t, b1p, out, band, mt, ntile, As, Bs); break;
    case 2:  gemm2_tile<64 >(hb, w1t, b1p, out, band, mt, ntile, As, Bs); break;
    default: gemm2_tile<128>(hb, w1t, b1p, out, band, mt, ntile, As, Bs); break;
  }
}

// ---------------- launch ----------------
extern "C" void kernel_launch(void* const* d_in, const int* in_sizes, int n_in,
                              void* d_out, int out_size, void* d_ws, size_t ws_size,
                              hipStream_t stream){
  const float* x  = (const float*)d_in[0];
  const float* W0 = (const float*)d_in[1];
  const float* b0 = (const float*)d_in[2];
  const float* W1 = (const float*)d_in[3];
  const float* b1 = (const float*)d_in[4];
  char* ws = (char*)d_ws;
  f16*   xh2  = (f16*)(ws);                       // 50,331,648 B (band-major)
  f16*   hbuf = (f16*)(ws + 50331648);            // 50,331,648 B
  f16*   w0t  = (f16*)(ws + 100663296);           // 25,165,824 B
  f16*   w1t  = (f16*)(ws + 125829120);           //  4,128,768 B
  float* b0p  = (float*)(ws + 129957888);         //     98,304 B
  float* b1p  = (float*)(ws + 130056192);         //     16,128 B

  prep <<<12652, 256, 0, stream>>>(x, W0, W1, b0, b1, xh2, w0t, w1t, b0p, b1p);
  gemm1<<<3072,  256, 0, stream>>>(xh2, w0t, b0p, hbuf);
  gemm2<<<640,   256, 0, stream>>>(hbuf, w1t, b1p, (float*)d_out);
}

// Round 5
// 329.395 us; speedup vs baseline: 1.3398x; 1.0119x over previous
//
#include <hip/hip_runtime.h>
#include <cstdint>
#include <cstddef>

// MaskEstimator: 24 independent 2-layer GLU MLPs (fp16 MFMA path).
// R5: gemm1 = R2's proven config (token-major xh, LDS-staged, 98us) + parity
// GLU epilogue + XCD swizzle. cast_x elementwise (no transpose). gemm2
// redesigned with 64-row tiles -> 1280 blocks (5/CU) to fix its latency/tail
// pathology (R4: 640 blocks, ~2.5/CU, est ~100us for 17 GFLOP).

typedef _Float16 f16;
typedef _Float16 f16x8 __attribute__((ext_vector_type(8)));
typedef float floatx4 __attribute__((ext_vector_type(4)));

#define BT 2048   // B*T
#define NB 24

__device__ __forceinline__ int band_di(int b){ return 8 << (b >> 2); }
__device__ __forceinline__ int band_off2(int b){
  int g = b >> 2;
  return 2 * (32 * ((1 << g) - 1) + (b & 3) * (8 << g));
}

__device__ __forceinline__ float fsigm(float x){
  return __builtin_amdgcn_rcpf(1.f + __expf(-x));
}
__device__ __forceinline__ float ftanh(float x){
  return 1.f - 2.f * __builtin_amdgcn_rcpf(1.f + __expf(2.f * x));
}

__device__ __forceinline__ void gl_lds16(const void* g, void* l){
  __builtin_amdgcn_global_load_lds(
      (const __attribute__((address_space(1))) unsigned int*)g,
      (__attribute__((address_space(3))) unsigned int*)l, 16, 0, 0);
}

// ---------------- cast_x: x f32 -> f16 token-major, elementwise ----------------
__global__ __launch_bounds__(256) void cast_x(const float4* __restrict__ in,
                                              f16* __restrict__ out){
  int t = blockIdx.x * 256 + threadIdx.x;   // x2 float4 each; 3145728 threads
  float4 v0 = in[2 * t];
  float4 v1 = in[2 * t + 1];
  f16x8 o = { (f16)v0.x,(f16)v0.y,(f16)v0.z,(f16)v0.w,
              (f16)v1.x,(f16)v1.y,(f16)v1.z,(f16)v1.w };
  *(f16x8*)(out + (size_t)t * 8) = o;
}

// ---------------- cast_w: W0 + W1 + biases ----------------
// blocks [0,6144): W0 (24,512,1024) -> w0t (24,1024,512), (a,g) col interleave
// blocks [6144,6396): W1 (512,4032) -> w1t (4032,512), band-local interleave
// blocks [6396,6508): biases permuted (fp32)
__global__ __launch_bounds__(256) void cast_w(const float* __restrict__ W0,
                                              const float* __restrict__ W1,
                                              const float* __restrict__ b0,
                                              const float* __restrict__ b1,
                                              f16* __restrict__ w0t,
                                              f16* __restrict__ w1t,
                                              float* __restrict__ b0p,
                                              float* __restrict__ b1p){
  __shared__ __align__(16) char smem[16640];
  int bid = blockIdx.x;
  int t = threadIdx.x;
  if (bid < 6144){
    float (*tile)[33] = (float(*)[33])smem;   // 64x33 floats = 8448B
    int dt   = bid & 7;
    int half = (bid >> 3) & 1;
    int g    = (bid >> 4) & 15;
    int band = bid >> 8;
    int c0 = half * 512 + g * 32;
    int d0 = dt * 64;
    int r  = t >> 2;
    int cs = (t & 3) * 8;
    const float* src = W0 + ((size_t)(band * 512 + d0 + r)) * 1024 + c0 + cs;
    float4 v0 = *(const float4*)src;
    float4 v1 = *(const float4*)(src + 4);
    tile[r][cs+0]=v0.x; tile[r][cs+1]=v0.y; tile[r][cs+2]=v0.z; tile[r][cs+3]=v0.w;
    tile[r][cs+4]=v1.x; tile[r][cs+5]=v1.y; tile[r][cs+6]=v1.z; tile[r][cs+7]=v1.w;
    __syncthreads();
    int i   = t >> 3;
    int ds8 = (t & 7) * 8;
    int prow = g * 64 + 2 * i + half;
    f16x8 o;
    #pragma unroll
    for (int k = 0; k < 8; ++k) o[k] = (f16)tile[ds8 + k][i];
    *(f16x8*)(w0t + ((size_t)(band * 1024 + prow)) * 512 + d0 + ds8) = o;
  } else if (bid < 6396){
    f16 (*tw)[520] = (f16(*)[520])smem;       // 16x520 f16 = 16640B
    int jt = bid - 6144;            // 0..251
    int j16 = jt * 16;
    int band = 23;
    for (int b = 0; b < 24; ++b){ if (j16 < band_off2(b + 1)) { band = b; break; } }
    int off2 = band_off2(band), di = band_di(band);
    int p0 = j16 - off2;
    int oca = off2 + (p0 >> 1);
    int ocg = oca + di;
    #pragma unroll
    for (int hh = 0; hh < 2; ++hh){
      int d = hh * 256 + t;
      const float* rowp = W1 + (size_t)d * 4032;
      float4 a0 = *(const float4*)(rowp + oca);
      float4 a1 = *(const float4*)(rowp + oca + 4);
      float4 g0 = *(const float4*)(rowp + ocg);
      float4 g1 = *(const float4*)(rowp + ocg + 4);
      float av[8] = {a0.x,a0.y,a0.z,a0.w,a1.x,a1.y,a1.z,a1.w};
      float gv[8] = {g0.x,g0.y,g0.z,g0.w,g1.x,g1.y,g1.z,g1.w};
      #pragma unroll
      for (int q = 0; q < 8; ++q){
        tw[2*q][d]   = (f16)av[q];
        tw[2*q+1][d] = (f16)gv[q];
      }
    }
    __syncthreads();
    int j = t & 15, dc = (t >> 4) * 32;
    f16x8 o[4];
    #pragma unroll
    for (int k = 0; k < 4; ++k) o[k] = *(const f16x8*)&tw[j][dc + k*8];
    f16* dst = w1t + (size_t)(j16 + j) * 512 + dc;
    #pragma unroll
    for (int k = 0; k < 4; ++k) *(f16x8*)(dst + k*8) = o[k];
  } else {
    int idx = (bid - 6396) * 256 + t;
    if (idx < NB * 1024){
      int p = idx & 1023;
      int base = idx & ~1023;
      b0p[idx] = b0[base + ((p & 1) ? 512 + (p >> 1) : (p >> 1))];
    } else {
      int j = idx - NB * 1024;
      if (j < 4032){
        int band = 23;
        for (int b = 0; b < 24; ++b){ if (j < band_off2(b + 1)) { band = b; break; } }
        int off2 = band_off2(band);
        int di = band_di(band);
        int p = j - off2;
        b1p[j] = b1[off2 + ((p & 1) ? di + (p >> 1) : (p >> 1))];
      }
    }
  }
}

// ---------------- GEMM1: R2 config (token-major xh) ----------------
// 128x128 tile, BK=64, 4 waves 2x2. grid 3072, XCD-contiguous swizzle.
__global__ __launch_bounds__(256) void gemm1(const f16* __restrict__ xh,
                                             const f16* __restrict__ w0t,
                                             const float* __restrict__ b0p,
                                             f16* __restrict__ h){
  __shared__ __align__(16) f16 As[128 * 64];
  __shared__ __align__(16) f16 Bs[128 * 64];
  int bid = blockIdx.x;
  int wid = (bid & 7) * 384 + (bid >> 3);   // 3 bands per XCD slice
  int band = wid >> 7;
  int mt = (wid >> 3) & 15;
  int nt = wid & 7;
  int t = threadIdx.x;
  int lane = t & 63, w = t >> 6;
  int wm = w & 1, wn = w >> 1;
  int quad = lane >> 4, lc = lane & 15;
  const int mrow0 = mt * 128;
  const int nrow0 = nt * 128;

  const char* gA[4]; const char* gB[4];
  f16* lA[4]; f16* lB[4];
  #pragma unroll
  for (int p = 0; p < 4; ++p){
    int idx = p * 256 + t;
    int r = idx >> 3, s = idx & 7, l = s ^ (r & 7);
    gA[p] = (const char*)(xh + ((size_t)(mrow0 + r) * 24 + band) * 512 + l * 8);
    gB[p] = (const char*)(w0t + ((size_t)(band * 1024 + nrow0 + r)) * 512 + l * 8);
    lA[p] = &As[idx * 8];
    lB[p] = &Bs[idx * 8];
  }
  int aoff[4], boff[4];
  #pragma unroll
  for (int i = 0; i < 4; ++i){
    int m = wm * 64 + i * 16 + lc;
    aoff[i] = (m * 64 + ((quad ^ (m & 7)) << 3)) * 2;
    int n = wn * 64 + i * 16 + lc;
    boff[i] = (n * 64 + ((quad ^ (n & 7)) << 3)) * 2;
  }
  const char* Ab = (const char*)As;
  const char* Bb = (const char*)Bs;

  floatx4 acc[4][4];
  #pragma unroll
  for (int i = 0; i < 4; ++i)
    #pragma unroll
    for (int j = 0; j < 4; ++j) acc[i][j] = floatx4{0.f, 0.f, 0.f, 0.f};

  for (int kb = 0; kb < 8; ++kb){
    #pragma unroll
    for (int p = 0; p < 4; ++p){ gl_lds16(gA[p], lA[p]); gA[p] += 128; }
    #pragma unroll
    for (int p = 0; p < 4; ++p){ gl_lds16(gB[p], lB[p]); gB[p] += 128; }
    __syncthreads();
    #pragma unroll
    for (int s2 = 0; s2 < 2; ++s2){
      f16x8 af[4], bf[4];
      #pragma unroll
      for (int i = 0; i < 4; ++i){
        af[i] = *(const f16x8*)(Ab + (aoff[i] ^ (s2 * 64)));
        bf[i] = *(const f16x8*)(Bb + (boff[i] ^ (s2 * 64)));
      }
      #pragma unroll
      for (int i = 0; i < 4; ++i)
        #pragma unroll
        for (int j = 0; j < 4; ++j)
          acc[i][j] = __builtin_amdgcn_mfma_f32_16x16x32_f16(af[i], bf[j], acc[i][j], 0, 0, 0);
    }
    __syncthreads();
  }
  // parity-split GLU epilogue
  #pragma unroll
  for (int j = 0; j < 4; ++j){
    int colp = nrow0 + wn * 64 + j * 16 + lc;
    float bias = b0p[band * 1024 + colp];
    #pragma unroll
    for (int i = 0; i < 4; ++i){
      int mbase = mrow0 + wm * 64 + i * 16 + quad * 4;
      #pragma unroll
      for (int r = 0; r < 4; ++r){
        float z = acc[i][j][r] + bias;
        float v = (lc & 1) ? fsigm(z) : ftanh(z);
        float vp = __shfl_xor(v, 1);
        if (!(lc & 1)){
          h[((size_t)band * BT + mbase + r) * 512 + (colp >> 1)] = (f16)(v * vp);
        }
      }
    }
  }
}

// ---------------- GEMM2: 64-row tiles, 1280 blocks ----------------
// BN<=64: 4 row-waves x 16 rows, NF=BN/16. BN=128: 2x2 waves, MF=2, NF=4.
template<int BN>
__device__ __forceinline__ void gemm2_tile(const f16* __restrict__ hb,
                                           const f16* __restrict__ w1t,
                                           const float* __restrict__ b1p,
                                           float* __restrict__ out,
                                           int band, int mt, int ntile,
                                           f16* As, f16* Bs){
  constexpr int MF = (BN == 128) ? 2 : 1;
  constexpr int NF = (BN == 128) ? 4 : BN / 16;
  int t = threadIdx.x;
  int lane = t & 63, w = t >> 6;
  int wrow = (BN == 128) ? (w & 1) : w;
  int wcol = (BN == 128) ? (w >> 1) : 0;
  int quad = lane >> 4, lc = lane & 15;
  int off2 = band_off2(band);
  int jbase = off2 + ntile * BN;

  constexpr int BU = BN * 8;               // B staging units (16B each)
  constexpr int BP = (BU + 255) / 256;
  const char* gA[2]; const char* gB[BP];
  f16* lA[2]; f16* lB[BP];
  #pragma unroll
  for (int p = 0; p < 2; ++p){             // A: 64 rows x 64 k = 512 units
    int idx = p * 256 + t;
    int r = idx >> 3, s = idx & 7, l = s ^ (r & 7);
    gA[p] = (const char*)(hb + ((size_t)(mt * 64 + r)) * 512 + l * 8);
    lA[p] = &As[idx * 8];
  }
  #pragma unroll
  for (int p = 0; p < BP; ++p){
    int idx = p * 256 + t;
    int r = idx >> 3, s = idx & 7, l = s ^ (r & 7);
    gB[p] = (const char*)(w1t + ((size_t)(jbase + r)) * 512 + l * 8);
    lB[p] = &Bs[idx * 8];
  }
  int aoff[MF], boff[NF];
  #pragma unroll
  for (int i = 0; i < MF; ++i){
    int m = wrow * (MF * 16) + i * 16 + lc;
    aoff[i] = (m * 64 + ((quad ^ (m & 7)) << 3)) * 2;
  }
  #pragma unroll
  for (int j = 0; j < NF; ++j){
    int n = wcol * 64 + j * 16 + lc;
    boff[j] = (n * 64 + ((quad ^ (n & 7)) << 3)) * 2;
  }
  const char* Ab = (const char*)As;
  const char* Bb = (const char*)Bs;

  floatx4 acc[MF][NF];
  #pragma unroll
  for (int i = 0; i < MF; ++i)
    #pragma unroll
    for (int j = 0; j < NF; ++j) acc[i][j] = floatx4{0.f, 0.f, 0.f, 0.f};

  for (int kb = 0; kb < 8; ++kb){
    #pragma unroll
    for (int p = 0; p < 2; ++p){ gl_lds16(gA[p], lA[p]); gA[p] += 128; }
    #pragma unroll
    for (int p = 0; p < BP; ++p){
      if ((BU % 256 == 0) || (p * 256 + t) < BU){
        gl_lds16(gB[p], lB[p]); gB[p] += 128;
      }
    }
    __syncthreads();
    #pragma unroll
    for (int s2 = 0; s2 < 2; ++s2){
      f16x8 af[MF], bf[NF];
      #pragma unroll
      for (int i = 0; i < MF; ++i)
        af[i] = *(const f16x8*)(Ab + (aoff[i] ^ (s2 * 64)));
      #pragma unroll
      for (int j = 0; j < NF; ++j)
        bf[j] = *(const f16x8*)(Bb + (boff[j] ^ (s2 * 64)));
      #pragma unroll
      for (int i = 0; i < MF; ++i)
        #pragma unroll
        for (int j = 0; j < NF; ++j)
          acc[i][j] = __builtin_amdgcn_mfma_f32_16x16x32_f16(af[i], bf[j], acc[i][j], 0, 0, 0);
    }
    __syncthreads();
  }
  int outbase = off2 >> 1;
  #pragma unroll
  for (int j = 0; j < NF; ++j){
    int p = ntile * BN + wcol * 64 + j * 16 + lc;
    float bias = b1p[off2 + p];
    #pragma unroll
    for (int i = 0; i < MF; ++i){
      int mbase = mt * 64 + wrow * (MF * 16) + i * 16 + quad * 4;
      #pragma unroll
      for (int r = 0; r < 4; ++r){
        float z = acc[i][j][r] + bias;
        float v = (lc & 1) ? fsigm(z) : ftanh(z);
        float vp = __shfl_xor(v, 1);
        if (!(lc & 1)){
          out[(size_t)(mbase + r) * 2016 + outbase + (p >> 1)] = v * vp;
        }
      }
    }
  }
}

// grid 1280: bands 0-15 (BN=2di<=128): 32 blocks each; bands 16-19: 64;
// bands 20-23: 128.
__global__ __launch_bounds__(256) void gemm2(const f16* __restrict__ h,
                                             const f16* __restrict__ w1t,
                                             const float* __restrict__ b1p,
                                             float* __restrict__ out){
  __shared__ __align__(16) f16 As[64 * 64];
  __shared__ __align__(16) f16 Bs[128 * 64];
  int bid = blockIdx.x;
  int band, mt, ntile, g;
  if (bid < 512){
    g = bid >> 7; band = g * 4 + ((bid >> 5) & 3); mt = bid & 31; ntile = 0;
  } else if (bid < 768){
    int rel = bid - 512; band = 16 + (rel >> 6);
    mt = rel & 31; ntile = (rel >> 5) & 1; g = 3;
  } else {
    int rel = bid - 768; band = 20 + (rel >> 7);
    mt = rel & 31; ntile = (rel >> 5) & 3; g = 3;
  }
  const f16* hb = h + ((size_t)band << 20);
  switch (g){
    case 0:  gemm2_tile<16 >(hb, w1t, b1p, out, band, mt, ntile, As, Bs); break;
    case 1:  gemm2_tile<32 >(hb, w1t, b1p, out, band, mt, ntile, As, Bs); break;
    case 2:  gemm2_tile<64 >(hb, w1t, b1p, out, band, mt, ntile, As, Bs); break;
    default: gemm2_tile<128>(hb, w1t, b1p, out, band, mt, ntile, As, Bs); break;
  }
}

// ---------------- launch ----------------
extern "C" void kernel_launch(void* const* d_in, const int* in_sizes, int n_in,
                              void* d_out, int out_size, void* d_ws, size_t ws_size,
                              hipStream_t stream){
  const float* x  = (const float*)d_in[0];
  const float* W0 = (const float*)d_in[1];
  const float* b0 = (const float*)d_in[2];
  const float* W1 = (const float*)d_in[3];
  const float* b1 = (const float*)d_in[4];
  char* ws = (char*)d_ws;
  f16*   xh   = (f16*)(ws);                       // 50,331,648 B (token-major)
  f16*   hbuf = (f16*)(ws + 50331648);            // 50,331,648 B (band-major)
  f16*   w0t  = (f16*)(ws + 100663296);           // 25,165,824 B
  f16*   w1t  = (f16*)(ws + 125829120);           //  4,128,768 B
  float* b0p  = (float*)(ws + 129957888);         //     98,304 B
  float* b1p  = (float*)(ws + 130056192);         //     16,128 B

  cast_x<<<12288, 256, 0, stream>>>((const float4*)x, xh);
  cast_w<<<6508,  256, 0, stream>>>(W0, W1, b0, b1, w0t, w1t, b0p, b1p);
  gemm1 <<<3072,  256, 0, stream>>>(xh, w0t, b0p, hbuf);
  gemm2 <<<1280,  256, 0, stream>>>(hbuf, w1t, b1p, (float*)d_out);
}